// Round 6
// baseline (377.886 us; speedup 1.0000x reference)
//
#include <hip/hip_runtime.h>
#include <hip/hip_bf16.h>

// Problem constants (match reference)
constexpr int NE  = 8;     // experts
constexpr int T   = 2048;  // tokens
constexpr int IN  = 2048;  // reduction dim
constexpr int OUT = 2048;  // output dim
constexpr int GS  = 64;    // quant group size
constexpr int G   = IN / GS;

// Tile config
constexpr int BM = 128;
constexpr int BN = 64;
constexpr int BK = 64;            // == GS: one scale/zero per K-tile
constexpr int NTILE = IN / BK;    // 32
constexpr int LDB = 64;           // no pad: XOR swizzle handles banks
constexpr int MAXMT = T / BM + NE;

using short8  = __attribute__((ext_vector_type(8))) short;
using short4v = __attribute__((ext_vector_type(4))) short;
using floatx4 = __attribute__((ext_vector_type(4))) float;
using int4v   = __attribute__((ext_vector_type(4))) int;
using float4v = __attribute__((ext_vector_type(4))) float;

// x fp32 -> bf16 pre-pass (x is the GEMM A operand)
__global__ __launch_bounds__(256)
void cvt_x_bf16(const float* __restrict__ x, __hip_bfloat16* __restrict__ xb) {
    const int i = (blockIdx.x * 256 + threadIdx.x) * 4;
    const float4 v = *(const float4*)(x + i);
    union { unsigned long long u; __hip_bfloat162 h2[2]; } p;
    p.h2[0] = __float22bfloat162_rn(float2{v.x, v.y});
    p.h2[1] = __float22bfloat162_rn(float2{v.z, v.w});
    *(unsigned long long*)(xb + i) = p.u;
}

__global__ __launch_bounds__(256, 3)
void hqq_grouped_gemm(const __hip_bfloat16* __restrict__ xb,
                      const int*   __restrict__ qw,
                      const float* __restrict__ snz,   // [E][G][OUT][2]
                      const int*   __restrict__ tpe,   // [E]
                      float* __restrict__ out) {
    const int tid = threadIdx.x;
    const int n0  = blockIdx.x * BN;

    // Compact grid: map mt slot -> (expert, m-tile) by walking tpe (r5-verified).
    const int mt = blockIdx.y;
    int e = -1, b0 = 0, b1 = 0, tm = 0;
    {
        int base = 0, rem = mt;
#pragma unroll
        for (int i = 0; i < NE; ++i) {
            const int c  = tpe[i];
            const int nt = (c + BM - 1) >> 7;   // ceil(c/128)
            if (e < 0) {
                if (rem < nt) { e = i; b0 = base; b1 = base + c; tm = rem; }
                else rem -= nt;
            }
            base += c;
        }
    }
    if (e < 0) return;
    const int row0 = b0 + tm * BM;

    // Triple-buffered B tile, XOR-swizzled (k ^= ((row>>2)&3)<<4 shorts).
    // Depth-3 register pipeline: per-tile period = load-latency / 3 (r5 model:
    // consume(t) - consume(t-depth) = latency; depth 2 measured 2840 cyc/tile).
    __shared__ __hip_bfloat16 Bs[3][BN][LDB];

    floatx4 acc[2][4];
#pragma unroll
    for (int i = 0; i < 2; ++i)
#pragma unroll
        for (int j = 0; j < 4; ++j)
            acc[i][j] = (floatx4){0.f, 0.f, 0.f, 0.f};

    // B-stage mapping: 4 consecutive n (dwordx4) x 4 consecutive k per thread
    const int n4  = (tid & 15) * 4;   // 16 n-groups cover BN=64
    const int kq4 = (tid >> 4) * 4;   // 16 k-groups cover BK=64
    const int wsz = (tid & 3) << 4;   // write swizzle: ((row>>2)&3)<<4, row=n4+nn -> tid&3

    // MFMA decomposition: 4 waves stacked in m (32 rows each)
    const int lane = tid & 63;
    const int wid  = tid >> 6;
    const int wm = wid * 32;
    const int lm = lane & 15;
    const int lk = (lane >> 4) * 8;
    const int rsz = ((lm >> 2) & 3) << 4;  // read swizzle: same row-function (rows j*16+lm)

    const int*    qbase  = qw + (size_t)e * IN * OUT + n0 + n4;
    const float2* szbase = (const float2*)snz + (size_t)e * G * OUT + n0 + n4;

    // A-fragment row pointers (clamped once; garbage rows never stored)
    const int r0c = min(row0 + wm + lm,      b1 - 1);
    const int r1c = min(row0 + wm + 16 + lm, b1 - 1);
    const __hip_bfloat16* ap0 = xb + (size_t)r0c * IN + lk;
    const __hip_bfloat16* ap1 = xb + (size_t)r1c * IN + lk;

    // ---- depth-3 register prefetch state (named sets, no runtime indexing) ----
    int4v   qvA[4], qvB[4], qvC[4];
    float4v szA[2], szB[2], szC[2];
    short8  afA[4], afB[4], afC[4];   // [ks2*2+i]: 2 k-halves x 2 row-groups

    auto issue_q = [&](int t, int4v (&qv)[4], float4v (&sz)[2]) {
        const int k0 = t * BK;
        const float4v* szp = (const float4v*)(szbase + (size_t)(k0 >> 6) * OUT);
        sz[0] = szp[0];
        sz[1] = szp[1];
#pragma unroll
        for (int kk = 0; kk < 4; ++kk)
            qv[kk] = *(const int4v*)(qbase + (size_t)(k0 + kq4 + kk) * OUT);
    };

    auto issue_af = [&](int t, short8 (&af)[4]) {
        const int k0 = t * BK;
        af[0] = *(const short8*)(ap0 + k0);
        af[1] = *(const short8*)(ap1 + k0);
        af[2] = *(const short8*)(ap0 + k0 + 32);
        af[3] = *(const short8*)(ap1 + k0 + 32);
    };

    // dequant 4x4 (k x n) micro-tile from regs -> LDS (4x ds_write_b64, swizzled)
    auto stage = [&](__hip_bfloat16 (&B)[BN][LDB], int4v (&qv)[4], float4v (&sz)[2]) {
#pragma unroll
        for (int nn = 0; nn < 4; ++nn) {
            const float sc = sz[nn >> 1][(nn & 1) * 2];
            const float cc = sz[nn >> 1][(nn & 1) * 2 + 1] - 8.0f * sc;  // (q-8)*s+z == q*s+cc
            union { short4v v; __hip_bfloat162 h2[2]; } pb;
            pb.h2[0] = __float22bfloat162_rn(float2{(float)qv[0][nn] * sc + cc,
                                                    (float)qv[1][nn] * sc + cc});
            pb.h2[1] = __float22bfloat162_rn(float2{(float)qv[2][nn] * sc + cc,
                                                    (float)qv[3][nn] * sc + cc});
            *(short4v*)&B[n4 + nn][kq4 ^ wsz] = pb.v;
        }
    };

    // MFMA over one K-tile; A-frags from prefetched registers (no vmem waits)
    auto mfma_tile = [&](const __hip_bfloat16 (&B)[BN][LDB], const short8 (&af)[4]) {
#pragma unroll
        for (int ks2 = 0; ks2 < 2; ++ks2) {
            short8 bfr[4];
#pragma unroll
            for (int j = 0; j < 4; ++j)
                bfr[j] = *(const short8*)&B[j * 16 + lm][(ks2 * 32 + lk) ^ rsz];
#pragma unroll
            for (int i = 0; i < 2; ++i)
#pragma unroll
                for (int j = 0; j < 4; ++j)
                    acc[i][j] = __builtin_amdgcn_mfma_f32_16x16x32_bf16(
                        af[ks2 * 2 + i], bfr[j], acc[i][j], 0, 0, 0);
        }
    };

    // Raw barrier: lgkm drain for LDS visibility; register prefetch loads
    // (vmcnt) legally stay in flight across it. sched_barrier(0) prevents
    // LDS ops from being scheduled across the barrier.
#define TILE_SYNC()                                          \
    asm volatile("s_waitcnt lgkmcnt(0)" ::: "memory");       \
    __builtin_amdgcn_s_barrier();                            \
    __builtin_amdgcn_sched_barrier(0)

    issue_q(0, qvA, szA);
    issue_q(1, qvB, szB);
    issue_q(2, qvC, szC);
    issue_af(0, afA);
    issue_af(1, afB);
    issue_af(2, afC);

    // main loop: tiles 0..29 in steps of 3; tail (30,31) handled after
    for (int t = 0; t + 2 < NTILE; t += 3) {
        const int tnA = (t + 3 < NTILE) ? t + 3 : NTILE - 1;
        const int tnB = (t + 4 < NTILE) ? t + 4 : NTILE - 1;
        const int tnC = (t + 5 < NTILE) ? t + 5 : NTILE - 1;

        stage(Bs[0], qvA, szA);
        issue_q(tnA, qvA, szA);
        TILE_SYNC();
        mfma_tile(Bs[0], afA);
        issue_af(tnA, afA);

        stage(Bs[1], qvB, szB);
        issue_q(tnB, qvB, szB);
        TILE_SYNC();
        mfma_tile(Bs[1], afB);
        issue_af(tnB, afB);

        stage(Bs[2], qvC, szC);
        issue_q(tnC, qvC, szC);
        TILE_SYNC();
        mfma_tile(Bs[2], afC);
        issue_af(tnC, afC);
    }
    // tail: tiles 30 (set A, issued at t=27 -> 30) and 31 (set B, -> 31)
    stage(Bs[0], qvA, szA);
    TILE_SYNC();
    mfma_tile(Bs[0], afA);
    stage(Bs[1], qvB, szB);
    TILE_SYNC();
    mfma_tile(Bs[1], afB);
#undef TILE_SYNC

    // ---- epilogue: plain stores. C/D layout col=lane&15, row=(lane>>4)*4+reg ----
    const int lq = (lane >> 4) * 4;
#pragma unroll
    for (int i = 0; i < 2; ++i) {
#pragma unroll
        for (int r = 0; r < 4; ++r) {
            const int row = row0 + wm + i * 16 + lq + r;
            if (row < b1) {
                float* op = out + (size_t)row * OUT + n0 + lm;
#pragma unroll
                for (int j = 0; j < 4; ++j)
                    op[j * 16] = acc[i][j][r];
            }
        }
    }
}

extern "C" void kernel_launch(void* const* d_in, const int* in_sizes, int n_in,
                              void* d_out, int out_size, void* d_ws, size_t ws_size,
                              hipStream_t stream) {
    const float* x   = (const float*)d_in[0];
    const int*   qw  = (const int*)d_in[1];
    const float* snz = (const float*)d_in[2];
    const int*   tpe = (const int*)d_in[3];
    float* out = (float*)d_out;
    __hip_bfloat16* xb = (__hip_bfloat16*)d_ws;   // needs T*IN*2 = 8.4 MB of ws

    cvt_x_bf16<<<(T * IN) / (256 * 4), 256, 0, stream>>>(x, xb);

    // Compact grid: every output row covered exactly once; plain stores
    // overwrite the poison; no memset, no atomics.
    dim3 grid(OUT / BN, MAXMT, 1);   // 32 x 24, ~96% active
    hqq_grouped_gemm<<<grid, 256, 0, stream>>>(xb, qw, snz, tpe, out);
}

// Round 8
// 248.288 us; speedup vs baseline: 1.5220x; 1.5220x over previous
//
#include <hip/hip_runtime.h>
#include <hip/hip_bf16.h>

// Problem constants (match reference)
constexpr int NE  = 8;     // experts
constexpr int T   = 2048;  // tokens
constexpr int IN  = 2048;  // reduction dim
constexpr int OUT = 2048;  // output dim
constexpr int GS  = 64;    // quant group size
constexpr int G   = IN / GS;

// Tile config
constexpr int BM = 128;
constexpr int BN = 64;
constexpr int BK = 64;            // == GS: one scale/zero per K-tile
constexpr int NTILE = IN / BK;    // 32
constexpr int LDB = 64;           // no pad: XOR swizzle handles banks
constexpr int MAXMT = T / BM + NE;

using short8  = __attribute__((ext_vector_type(8))) short;
using short4v = __attribute__((ext_vector_type(4))) short;
using floatx4 = __attribute__((ext_vector_type(4))) float;
using int4v   = __attribute__((ext_vector_type(4))) int;
using float4v = __attribute__((ext_vector_type(4))) float;

// x fp32 -> bf16 pre-pass (x is the GEMM A operand)
__global__ __launch_bounds__(256)
void cvt_x_bf16(const float* __restrict__ x, __hip_bfloat16* __restrict__ xb) {
    const int i = (blockIdx.x * 256 + threadIdx.x) * 4;
    const float4 v = *(const float4*)(x + i);
    union { unsigned long long u; __hip_bfloat162 h2[2]; } p;
    p.h2[0] = __float22bfloat162_rn(float2{v.x, v.y});
    p.h2[1] = __float22bfloat162_rn(float2{v.z, v.w});
    *(unsigned long long*)(xb + i) = p.u;
}

__global__ __launch_bounds__(256, 3)
void hqq_grouped_gemm(const __hip_bfloat16* __restrict__ xb,
                      const int*   __restrict__ qw,
                      const float* __restrict__ snz,   // [E][G][OUT][2]
                      const int*   __restrict__ tpe,   // [E]
                      float* __restrict__ out) {
    const int tid = threadIdx.x;
    const int n0  = blockIdx.x * BN;

    // Compact grid: map mt slot -> (expert, m-tile) by walking tpe (r5-verified).
    const int mt = blockIdx.y;
    int e = -1, b0 = 0, b1 = 0, tm = 0;
    {
        int base = 0, rem = mt;
#pragma unroll
        for (int i = 0; i < NE; ++i) {
            const int c  = tpe[i];
            const int nt = (c + BM - 1) >> 7;   // ceil(c/128)
            if (e < 0) {
                if (rem < nt) { e = i; b0 = base; b1 = base + c; tm = rem; }
                else rem -= nt;
            }
            base += c;
        }
    }
    if (e < 0) return;
    const int row0 = b0 + tm * BM;

    // Double-buffered B tile, XOR-swizzled (k ^= ((row>>2)&3)<<4 shorts).
    __shared__ __hip_bfloat16 Bs[2][BN][LDB];

    floatx4 acc[2][4];
#pragma unroll
    for (int i = 0; i < 2; ++i)
#pragma unroll
        for (int j = 0; j < 4; ++j)
            acc[i][j] = (floatx4){0.f, 0.f, 0.f, 0.f};

    // B-stage mapping: 4 consecutive n (dwordx4) x 4 consecutive k per thread
    const int n4  = (tid & 15) * 4;   // 16 n-groups cover BN=64
    const int kq4 = (tid >> 4) * 4;   // 16 k-groups cover BK=64
    const int wsz = (tid & 3) << 4;   // write swizzle: ((row>>2)&3)<<4, row=n4+nn -> tid&3

    // MFMA decomposition: 4 waves stacked in m (32 rows each)
    const int lane = tid & 63;
    const int wid  = tid >> 6;
    const int wm = wid * 32;
    const int lm = lane & 15;
    const int lk = (lane >> 4) * 8;
    const int rsz = ((lm >> 2) & 3) << 4;  // read swizzle: same row-function (rows j*16+lm)

    const int*    qbase  = qw + (size_t)e * IN * OUT + n0 + n4;
    const float2* szbase = (const float2*)snz + (size_t)e * G * OUT + n0 + n4;

    // A-fragment row pointers (clamped once; garbage rows never stored)
    const int r0c = min(row0 + wm + lm,      b1 - 1);
    const int r1c = min(row0 + wm + 16 + lm, b1 - 1);
    const __hip_bfloat16* ap0 = xb + (size_t)r0c * IN + lk;
    const __hip_bfloat16* ap1 = xb + (size_t)r1c * IN + lk;

    // ---- ASM-pinned depth-2 prefetch state.
    // r5/r6 lesson: intrinsic-level "prefetch" is SUNK to its use (r5,
    // VGPR=76: sets never lived) or SPILLED (r6: 287MB scratch traffic).
    // asm volatile loads issue in program order, can't be sunk, and their
    // outputs must live in registers. r7 (depth-3, ~136 pinned regs) blew
    // the 168-reg cap and aborted; depth-2 pins 112 -> peak ~150.
    int4v   qvX[4], qvY[4];     // qweight
    float4v szX[2], szY[2];     // scales/zeros
    short8  afA[4], afB[4];     // A-fragments [ks2*2+i]

#define GLOAD16(dst, addr) \
    asm volatile("global_load_dwordx4 %0, %1, off" : "=v"(dst) : "v"(addr))
#define GLOAD16_OFF(dst, addr, B) \
    asm volatile("global_load_dwordx4 %0, %1, off offset:" #B : "=v"(dst) : "v"(addr))

    // issue 6 loads for K-tile t (2 sz + 4 qw)
    auto issue_q = [&](int t, int4v (&qv)[4], float4v (&sz)[2]) {
        const int k0 = t * BK;
        const float4v* szp = (const float4v*)(szbase + (size_t)(k0 >> 6) * OUT);
        GLOAD16(sz[0], szp);
        GLOAD16_OFF(sz[1], szp, 16);
#pragma unroll
        for (int kk = 0; kk < 4; ++kk) {
            const int* qp = qbase + (size_t)(k0 + kq4 + kk) * OUT;
            GLOAD16(qv[kk], qp);
        }
    };

    // issue 4 loads for the A-fragments of K-tile t
    auto issue_af = [&](int t, short8 (&af)[4]) {
        const __hip_bfloat16* p0 = ap0 + t * BK;
        const __hip_bfloat16* p1 = ap1 + t * BK;
        GLOAD16(af[0], p0);
        GLOAD16(af[1], p1);
        GLOAD16_OFF(af[2], p0, 64);   // +32 bf16
        GLOAD16_OFF(af[3], p1, 64);
    };

    // dequant 4x4 (k x n) micro-tile from regs -> LDS (4x ds_write_b64, swizzled)
    auto stage = [&](__hip_bfloat16 (&B)[BN][LDB], int4v (&qv)[4], float4v (&sz)[2]) {
#pragma unroll
        for (int nn = 0; nn < 4; ++nn) {
            const float sc = sz[nn >> 1][(nn & 1) * 2];
            const float cc = sz[nn >> 1][(nn & 1) * 2 + 1] - 8.0f * sc;  // (q-8)*s+z == q*s+cc
            union { short4v v; __hip_bfloat162 h2[2]; } pb;
            pb.h2[0] = __float22bfloat162_rn(float2{(float)qv[0][nn] * sc + cc,
                                                    (float)qv[1][nn] * sc + cc});
            pb.h2[1] = __float22bfloat162_rn(float2{(float)qv[2][nn] * sc + cc,
                                                    (float)qv[3][nn] * sc + cc});
            *(short4v*)&B[n4 + nn][kq4 ^ wsz] = pb.v;
        }
    };

    // MFMA over one K-tile; A-frags from asm-prefetched registers
    auto mfma_tile = [&](const __hip_bfloat16 (&B)[BN][LDB], const short8 (&af)[4]) {
#pragma unroll
        for (int ks2 = 0; ks2 < 2; ++ks2) {
            short8 bfr[4];
#pragma unroll
            for (int j = 0; j < 4; ++j)
                bfr[j] = *(const short8*)&B[j * 16 + lm][(ks2 * 32 + lk) ^ rsz];
#pragma unroll
            for (int i = 0; i < 2; ++i)
#pragma unroll
                for (int j = 0; j < 4; ++j)
                    acc[i][j] = __builtin_amdgcn_mfma_f32_16x16x32_bf16(
                        af[ks2 * 2 + i], bfr[j], acc[i][j], 0, 0, 0);
        }
    };

    // Phase t: wait Q(t) [WA], stage->LDS, reissue Q(t+2); lgkm-drain+barrier;
    // wait F(t) [WE], MFMA, reissue F(t+2).
    // Issue stream: Q0(6) Q1(6) F0(4) F1(4) | per phase: Q(t+2)(6) F(t+2)(4).
    // steady WA: after Q(t): F(t)4 + Q(t+1)6 + F(t+1)4            = 14
    // steady WE: after F(t): Q(t+1)6 + F(t+1)4 + Q(t+2)6          = 16
    //   (WA leaves Q(t+1)/F(t+1) in flight; WE leaves Q(t+1)/F(t+1)/Q(t+2):
    //    genuine depth-2 pipelining, verified by stream simulation.)
    // phase 0: WA = Q1+F0+F1 = 14; WE = F1+Q2 = 10.
    // phase 1: WA = F0+F1+Q2+F2 = 18; WE = Q2+F2+Q3 = 16.
    // rule #18: sched_barrier(0) after every manual wait.
#define PHASE(TT, QS, AS, BB, WA, WE)                                   \
    asm volatile("s_waitcnt vmcnt(" #WA ")" ::: "memory");              \
    __builtin_amdgcn_sched_barrier(0);                                  \
    stage(Bs[BB], qv##QS, sz##QS);                                      \
    issue_q((TT) + 2 < NTILE ? (TT) + 2 : NTILE - 1, qv##QS, sz##QS);   \
    asm volatile("s_waitcnt lgkmcnt(0)" ::: "memory");                  \
    __builtin_amdgcn_s_barrier();                                       \
    __builtin_amdgcn_sched_barrier(0);                                  \
    asm volatile("s_waitcnt vmcnt(" #WE ")" ::: "memory");              \
    __builtin_amdgcn_sched_barrier(0);                                  \
    mfma_tile(Bs[BB], af##AS);                                          \
    issue_af((TT) + 2 < NTILE ? (TT) + 2 : NTILE - 1, af##AS);

    // prologue: exact issue order Q0 Q1 F0 F1 (wait counts depend on it)
    issue_q(0, qvX, szX);
    issue_q(1, qvY, szY);
    issue_af(0, afA);
    issue_af(1, afB);

    // peeled phases 0,1; then steady 2..31 (parity: even=X/A/buf0, odd=Y/B/buf1)
    PHASE(0, X, A, 0, 14, 10)
    PHASE(1, Y, B, 1, 18, 16)
    for (int it = 0; it < 15; ++it) {
        const int t = 2 + it * 2;
        PHASE(t,     X, A, 0, 14, 16)
        PHASE(t + 1, Y, B, 1, 14, 16)
    }
#undef PHASE
#undef GLOAD16
#undef GLOAD16_OFF

    // ---- epilogue: plain stores. C/D layout col=lane&15, row=(lane>>4)*4+reg ----
    const int lq = (lane >> 4) * 4;
#pragma unroll
    for (int i = 0; i < 2; ++i) {
#pragma unroll
        for (int r = 0; r < 4; ++r) {
            const int row = row0 + wm + i * 16 + lq + r;
            if (row < b1) {
                float* op = out + (size_t)row * OUT + n0 + lm;
#pragma unroll
                for (int j = 0; j < 4; ++j)
                    op[j * 16] = acc[i][j][r];
            }
        }
    }
}

extern "C" void kernel_launch(void* const* d_in, const int* in_sizes, int n_in,
                              void* d_out, int out_size, void* d_ws, size_t ws_size,
                              hipStream_t stream) {
    const float* x   = (const float*)d_in[0];
    const int*   qw  = (const int*)d_in[1];
    const float* snz = (const float*)d_in[2];
    const int*   tpe = (const int*)d_in[3];
    float* out = (float*)d_out;
    __hip_bfloat16* xb = (__hip_bfloat16*)d_ws;   // needs T*IN*2 = 8.4 MB of ws

    cvt_x_bf16<<<(T * IN) / (256 * 4), 256, 0, stream>>>(x, xb);

    // Compact grid: every output row covered exactly once; plain stores
    // overwrite the poison; no memset, no atomics.
    dim3 grid(OUT / BN, MAXMT, 1);   // 32 x 24, ~96% active
    hqq_grouped_gemm<<<grid, 256, 0, stream>>>(xb, qw, snz, tpe, out);
}

// Round 11
// 244.880 us; speedup vs baseline: 1.5431x; 1.0139x over previous
//
#include <hip/hip_runtime.h>
#include <hip/hip_bf16.h>

// Problem constants (match reference)
constexpr int NE  = 8;     // experts
constexpr int T   = 2048;  // tokens
constexpr int IN  = 2048;  // reduction dim
constexpr int OUT = 2048;  // output dim
constexpr int GS  = 64;    // quant group size
constexpr int G   = IN / GS;

// Tile config
constexpr int BM = 128;
constexpr int BN = 64;
constexpr int BK = 64;            // == GS: one scale/zero per K-tile
constexpr int NTILE = IN / BK;    // 32
constexpr int HT  = NTILE / 2;    // 16 tiles per chain
constexpr int LDB = 64;           // no pad: XOR swizzle handles banks
constexpr int MAXMT = T / BM + NE;

using short8  = __attribute__((ext_vector_type(8))) short;
using short4v = __attribute__((ext_vector_type(4))) short;
using floatx4 = __attribute__((ext_vector_type(4))) float;
using int4v   = __attribute__((ext_vector_type(4))) int;
using float4v = __attribute__((ext_vector_type(4))) float;

// x fp32 -> bf16 pre-pass (x is the GEMM A operand)
__global__ __launch_bounds__(256)
void cvt_x_bf16(const float* __restrict__ x, __hip_bfloat16* __restrict__ xb) {
    const int i = (blockIdx.x * 256 + threadIdx.x) * 4;
    const float4 v = *(const float4*)(x + i);
    union { unsigned long long u; __hip_bfloat162 h2[2]; } p;
    p.h2[0] = __float22bfloat162_rn(float2{v.x, v.y});
    p.h2[1] = __float22bfloat162_rn(float2{v.z, v.w});
    *(unsigned long long*)(xb + i) = p.u;
}

// 512 threads = 2 K-chains x 4 waves. Each chain is an exact clone of the
// r8-verified pipeline (asm-pinned depth-2 Q + af, per-wave vmcnt counts
// UNCHANGED since vm counters are per-wave). Chain c handles tiles
// [c*HT, c*HT+HT). Block wall-time = 16 phases instead of 32; chain 1's
// accumulators are combined via LDS at the end (no atomics, no extra ws).
__global__ __launch_bounds__(512, 2)
void hqq_grouped_gemm(const __hip_bfloat16* __restrict__ xb,
                      const int*   __restrict__ qw,
                      const float* __restrict__ snz,   // [E][G][OUT][2]
                      const int*   __restrict__ tpe,   // [E]
                      float* __restrict__ out) {
    const int tid = threadIdx.x;
    const int n0  = blockIdx.x * BN;

    // Compact grid: map mt slot -> (expert, m-tile) by walking tpe (r5-verified).
    const int mt = blockIdx.y;
    int e = -1, b0 = 0, b1 = 0, tm = 0;
    {
        int base = 0, rem = mt;
#pragma unroll
        for (int i = 0; i < NE; ++i) {
            const int c  = tpe[i];
            const int nt = (c + BM - 1) >> 7;   // ceil(c/128)
            if (e < 0) {
                if (rem < nt) { e = i; b0 = base; b1 = base + c; tm = rem; }
                else rem -= nt;
            }
            base += c;
        }
    }
    if (e < 0) return;   // block-uniform
    const int row0 = b0 + tm * BM;

    // [chain][dbuf] B tiles, XOR-swizzled (r2-verified). 32KB total;
    // reused as the f32 combine buffer in the epilogue.
    __shared__ __hip_bfloat16 Bs[2][2][BN][LDB];

    floatx4 acc[2][4];
#pragma unroll
    for (int i = 0; i < 2; ++i)
#pragma unroll
        for (int j = 0; j < 4; ++j)
            acc[i][j] = (floatx4){0.f, 0.f, 0.f, 0.f};

    const int ct    = tid & 255;   // chain-local tid (r8's tid role)
    const int chain = tid >> 8;    // 0 or 1
    const int lane  = tid & 63;
    const int cwid  = (tid >> 6) & 3;   // wave-in-chain

    // B-stage mapping (chain-local, r8-identical)
    const int n4  = (ct & 15) * 4;
    const int kq4 = ((ct >> 4) & 15) * 4;
    const int wsz = (ct & 3) << 4;   // write swizzle ((row>>2)&3)<<4

    // MFMA decomposition (per chain: 4 waves x 32 rows)
    const int wm  = cwid * 32;
    const int lm  = lane & 15;
    const int hi  = lane >> 4;
    const int rsz = ((lm >> 2) & 3) << 4;  // read swizzle

    const int*    qbase  = qw + (size_t)e * IN * OUT + n0 + n4;
    const float2* szbase = (const float2*)snz + (size_t)e * G * OUT + n0 + n4;

    // A-fragment row pointers (clamped once; garbage rows never stored)
    const int r0c = min(row0 + wm + lm,      b1 - 1);
    const int r1c = min(row0 + wm + 16 + lm, b1 - 1);
    const __hip_bfloat16* ap0 = xb + (size_t)r0c * IN + (hi * 8);
    const __hip_bfloat16* ap1 = xb + (size_t)r1c * IN + (hi * 8);

    // chain k-range
    const int tb = chain * HT;        // first global tile of this chain
    const int tl = tb + HT - 1;       // last global tile of this chain

    // ---- asm-pinned depth-2 prefetch state (r8-proven budget) ----
    int4v   qvX[4], qvY[4];
    float4v szX[2], szY[2];
    short8  afA[4], afB[4];   // [ks2*2+i]

#define GLOAD16(dst, addr) \
    asm volatile("global_load_dwordx4 %0, %1, off" : "=v"(dst) : "v"(addr))
#define GLOAD16_OFF(dst, addr, B) \
    asm volatile("global_load_dwordx4 %0, %1, off offset:" #B : "=v"(dst) : "v"(addr))

    // 6 loads for global K-tile t (2 sz + 4 qw)
    auto issue_q = [&](int t, int4v (&qv)[4], float4v (&sz)[2]) {
        const int k0 = t * BK;
        const float4v* szp = (const float4v*)(szbase + (size_t)(k0 >> 6) * OUT);
        GLOAD16(sz[0], szp);
        GLOAD16_OFF(sz[1], szp, 16);
#pragma unroll
        for (int kk = 0; kk < 4; ++kk) {
            const int* qp = qbase + (size_t)(k0 + kq4 + kk) * OUT;
            GLOAD16(qv[kk], qp);
        }
    };

    // 4 loads for the A-fragments of global K-tile t
    auto issue_af = [&](int t, short8 (&af)[4]) {
        const __hip_bfloat16* p0 = ap0 + t * BK;
        const __hip_bfloat16* p1 = ap1 + t * BK;
        GLOAD16(af[0], p0);
        GLOAD16(af[1], p1);
        GLOAD16_OFF(af[2], p0, 64);   // +32 bf16
        GLOAD16_OFF(af[3], p1, 64);
    };

    // dequant 4x4 micro-tile from regs -> LDS (4x ds_write_b64, swizzled)
    auto stage = [&](__hip_bfloat16 (&B)[BN][LDB], int4v (&qv)[4], float4v (&sz)[2]) {
#pragma unroll
        for (int nn = 0; nn < 4; ++nn) {
            const float sc = sz[nn >> 1][(nn & 1) * 2];
            const float cc = sz[nn >> 1][(nn & 1) * 2 + 1] - 8.0f * sc;  // (q-8)*s+z == q*s+cc
            union { short4v v; __hip_bfloat162 h2[2]; } pb;
            pb.h2[0] = __float22bfloat162_rn(float2{(float)qv[0][nn] * sc + cc,
                                                    (float)qv[1][nn] * sc + cc});
            pb.h2[1] = __float22bfloat162_rn(float2{(float)qv[2][nn] * sc + cc,
                                                    (float)qv[3][nn] * sc + cc});
            *(short4v*)&B[n4 + nn][kq4 ^ wsz] = pb.v;
        }
    };

    // MFMA over one K-tile; A-frags from asm-prefetched registers
    auto mfma_tile = [&](const __hip_bfloat16 (&B)[BN][LDB], const short8 (&af)[4]) {
#pragma unroll
        for (int ks2 = 0; ks2 < 2; ++ks2) {
            short8 bfr[4];
#pragma unroll
            for (int j = 0; j < 4; ++j)
                bfr[j] = *(const short8*)&B[j * 16 + lm][(ks2 * 32 + hi * 8) ^ rsz];
#pragma unroll
            for (int i = 0; i < 2; ++i)
#pragma unroll
                for (int j = 0; j < 4; ++j)
                    acc[i][j] = __builtin_amdgcn_mfma_f32_16x16x32_bf16(
                        af[ks2 * 2 + i], bfr[j], acc[i][j], 0, 0, 0);
        }
    };

    // r8-verified phase (per-wave vmcnt identical; barrier now joins 8 waves
    // of two symmetric chains). LL = local phase index; global tile = tb+LL.
    // Issue stream per wave: Q0(6) Q1(6) F0(4) F1(4) | per phase Q(+2)(6) F(+2)(4).
    // steady WA=14 (drain Q(t)), WE=16 (drain F(t)); peeled: P0=(14,10), P1=(18,16).
#define PHASE(LL, QS, AS, BB, WA, WE)                                   \
    asm volatile("s_waitcnt vmcnt(" #WA ")" ::: "memory");              \
    __builtin_amdgcn_sched_barrier(0);                                  \
    stage(Bs[chain][BB], qv##QS, sz##QS);                               \
    issue_q((LL) + 2 < HT ? tb + (LL) + 2 : tl, qv##QS, sz##QS);        \
    asm volatile("s_waitcnt lgkmcnt(0)" ::: "memory");                  \
    __builtin_amdgcn_s_barrier();                                       \
    __builtin_amdgcn_sched_barrier(0);                                  \
    asm volatile("s_waitcnt vmcnt(" #WE ")" ::: "memory");              \
    __builtin_amdgcn_sched_barrier(0);                                  \
    mfma_tile(Bs[chain][BB], af##AS);                                   \
    issue_af((LL) + 2 < HT ? tb + (LL) + 2 : tl, af##AS);

    // prologue: FIFO order Q0 Q1 F0 F1 (counts depend on it)
    issue_q(tb,     qvX, szX);
    issue_q(tb + 1, qvY, szY);
    issue_af(tb,     afA);
    issue_af(tb + 1, afB);

    PHASE(0, X, A, 0, 14, 10)
    PHASE(1, Y, B, 1, 18, 16)
    for (int it = 0; it < 7; ++it) {
        const int p = 2 + it * 2;
        PHASE(p,     X, A, 0, 14, 16)
        PHASE(p + 1, Y, B, 1, 14, 16)
    }
#undef PHASE
#undef GLOAD16
#undef GLOAD16_OFF

    // ---- combine: chain1 acc -> LDS -> chain0 adds, stores ----
    __syncthreads();   // all reads of Bs done; drains stray tail loads too
    float* cbuf = (float*)&Bs[0][0][0][0];   // 8192 floats == 32KB == sizeof(Bs)
    if (chain == 1) {
#pragma unroll
        for (int i = 0; i < 2; ++i)
#pragma unroll
            for (int j = 0; j < 4; ++j)
#pragma unroll
                for (int r = 0; r < 4; ++r)
                    // k-major layout: lane-stride 4B -> conflict-free
                    cbuf[((i * 4 + j) * 4 + r) * 256 + cwid * 64 + lane] = acc[i][j][r];
    }
    __syncthreads();

    if (chain == 0) {
        // C/D layout col=lane&15, row=(lane>>4)*4+reg
        const int lq = hi * 4;
#pragma unroll
        for (int i = 0; i < 2; ++i) {
#pragma unroll
            for (int r = 0; r < 4; ++r) {
                const int row = row0 + wm + i * 16 + lq + r;
                if (row < b1) {
                    float* op = out + (size_t)row * OUT + n0 + lm;
#pragma unroll
                    for (int j = 0; j < 4; ++j)
                        op[j * 16] = acc[i][j][r]
                                   + cbuf[((i * 4 + j) * 4 + r) * 256 + cwid * 64 + lane];
                }
            }
        }
    }
}

extern "C" void kernel_launch(void* const* d_in, const int* in_sizes, int n_in,
                              void* d_out, int out_size, void* d_ws, size_t ws_size,
                              hipStream_t stream) {
    const float* x   = (const float*)d_in[0];
    const int*   qw  = (const int*)d_in[1];
    const float* snz = (const float*)d_in[2];
    const int*   tpe = (const int*)d_in[3];
    float* out = (float*)d_out;
    __hip_bfloat16* xb = (__hip_bfloat16*)d_ws;   // needs T*IN*2 = 8.4 MB of ws

    cvt_x_bf16<<<(T * IN) / (256 * 4), 256, 0, stream>>>(x, xb);

    // Compact grid: every output row covered exactly once; plain stores
    // overwrite the poison; no memset, no atomics.
    dim3 grid(OUT / BN, MAXMT, 1);   // 32 x 24, 512-thread blocks
    hqq_grouped_gemm<<<grid, 512, 0, stream>>>(xb, qw, snz, tpe, out);
}